// Round 8
// baseline (188.029 us; speedup 1.0000x reference)
//
#include <hip/hip_runtime.h>
#include <math.h>

// Problem constants (fixed by setup_inputs)
#define BS 4
#define NH 8
#define TT 1024         // T = 32*32
#define WROWS 1536      // 3*NH*CH
#define NOBJ 8
#define NT 65536        // per-bh tensor elems (64*1024)

// Workspace layout (short element offsets)
#define QNT_OFF  0
#define KNT_OFF  2097152
#define VNCS_OFF 4194304
#define QFT_OFF  6291456
#define KFT_OFF  8388608
#define VFT_OFF  10485760
#define ULIST_OFF 12582912          // 4*1024 ushorts
#define UCNT_BYTE_OFF 25174016      // 4 ints

typedef __attribute__((ext_vector_type(8))) short short8;
typedef __attribute__((ext_vector_type(4))) float v4f;

#if __has_builtin(__builtin_amdgcn_exp2f)
#define EXP2(x) __builtin_amdgcn_exp2f(x)
#else
#define EXP2(x) exp2f(x)
#endif

__device__ __forceinline__ short f2bf(float f) {
    unsigned u = __float_as_uint(f);
    u = (u + 0x7FFF + ((u >> 16) & 1)) >> 16;   // RNE
    return (short)u;
}
__device__ __forceinline__ unsigned p2(float a, float b) {
    return (unsigned)(unsigned short)f2bf(a) | ((unsigned)(unsigned short)f2bf(b) << 16);
}
// truncating bf16 pack (P matrix only; l summed in fp32)
__device__ __forceinline__ unsigned p2t(float a, float b) {
    return (__float_as_uint(a) >> 16) | (__float_as_uint(b) & 0xFFFF0000u);
}

__device__ __forceinline__ void get_region(const float* __restrict__ bb,
                                           int& i0, int& j0, int& hh, int& ww) {
    float x = bb[0], y = bb[1], bw = bb[2], bh = bb[3];
    float i0f = fminf(31.0f, floorf(y * 32.0f));
    float j0f = fminf(31.0f, floorf(x * 32.0f));
    float i1f = i0f + fmaxf(1.0f, ceilf(bh * 32.0f));
    float j1f = j0f + fmaxf(1.0f, ceilf(bw * 32.0f));
    i0 = (int)i0f; j0 = (int)j0f;
    int i1 = min(32, (int)i1f);
    int j1 = min(32, (int)j1f);
    hh = i1 - i0; ww = j1 - j0;
}

// ---------------------------------------------------------------------------
// Kernel 0: per-batch uncovered-cell list (prefix-scan compaction).
// grid 4 (b), 256 threads, thread i handles t in [4i, 4i+4).
// ---------------------------------------------------------------------------
__global__ __launch_bounds__(256)
void list_kernel(const float* __restrict__ bboxes,
                 unsigned short* __restrict__ ulist, int* __restrict__ ucnt) {
    int b = blockIdx.x, tid = threadIdx.x;
    int I0[NOBJ], I1[NOBJ], J0[NOBJ], J1[NOBJ];
#pragma unroll
    for (int o = 0; o < NOBJ; ++o) {
        int i0, j0, hh, ww;
        get_region(&bboxes[(b * NOBJ + o) * 5], i0, j0, hh, ww);
        I0[o] = i0; I1[o] = i0 + hh; J0[o] = j0; J1[o] = j0 + ww;
    }
    int u[4], uc = 0;
#pragma unroll
    for (int j = 0; j < 4; ++j) {
        int t = tid * 4 + j, ti = t >> 5, tj = t & 31;
        bool cov = false;
#pragma unroll
        for (int o = 0; o < NOBJ; ++o)
            cov = cov || (ti >= I0[o] && ti < I1[o] && tj >= J0[o] && tj < J1[o]);
        u[j] = cov ? 0 : 1; uc += u[j];
    }
    int lane = tid & 63, w = tid >> 6;
    int s = uc;
#pragma unroll
    for (int d = 1; d < 64; d <<= 1) {
        int v = __shfl_up(s, d, 64);
        if (lane >= d) s += v;
    }
    __shared__ int wsum[4];
    if (lane == 63) wsum[w] = s;
    __syncthreads();
    int off = 0;
    for (int i = 0; i < w; ++i) off += wsum[i];
    int base = off + s - uc;
    int k = 0;
#pragma unroll
    for (int j = 0; j < 4; ++j) {
        if (u[j]) { ulist[b * 1024 + base + k] = (unsigned short)(tid * 4 + j); ++k; }
    }
    if (tid == 0) ucnt[b] = wsum[0] + wsum[1] + wsum[2] + wsum[3];
}

// ---------------------------------------------------------------------------
// Kernel 1: fused projection + layout conversion to bf16 (verified R7).
// Q sections carry 0.125*log2(e) so attention uses exp2 directly.
// ---------------------------------------------------------------------------
__global__ __launch_bounds__(256)
void fuse_kernel(const float* __restrict__ qkv, const float* __restrict__ nEmb,
                 const float* __restrict__ pEmb, const float* __restrict__ W,
                 short* __restrict__ wsS) {
    __shared__ float WtT[64][68];
    __shared__ float En[64][64];
    __shared__ float Ep[64][64];
    short* sbufA = (short*)&WtT[0][0];
    short* sbufB = (short*)&En[0][0];
    int t0 = blockIdx.x * 64;
    int r0 = blockIdx.y * 64;
    int b  = blockIdx.z;
    int tid = threadIdx.x;
    int half = tid >> 4;
    int q4 = (tid & 15) * 4;
    int tr = tid >> 4, tc = tid & 15;
    float4 xq[4];
#pragma unroll
    for (int i = 0; i < 4; ++i)
        xq[i] = *(const float4*)&qkv[(b * WROWS + r0 + tr * 4 + i) * TT + t0 + tc * 4];
#pragma unroll
    for (int p = 0; p < 4; ++p) {
        int rr = p * 16 + half;
        float4 w4 = *(const float4*)&W[(r0 + rr) * 64 + q4];
        WtT[q4 + 0][rr] = w4.x; WtT[q4 + 1][rr] = w4.y;
        WtT[q4 + 2][rr] = w4.z; WtT[q4 + 3][rr] = w4.w;
        int e = p * 16 + half;
        *(float4*)&En[e][q4] = *(const float4*)&nEmb[(b * 64 + e) * TT + t0 + q4];
        *(float4*)&Ep[e][q4] = *(const float4*)&pEmb[(b * 64 + e) * TT + t0 + q4];
    }
    __syncthreads();
    float an[4][4] = {{0.f}}, ap[4][4] = {{0.f}};
#pragma unroll 8
    for (int e = 0; e < 64; ++e) {
        float4 w4 = *(const float4*)&WtT[e][tr * 4];
        float4 n4 = *(const float4*)&En[e][tc * 4];
        float4 p4 = *(const float4*)&Ep[e][tc * 4];
        float w[4]  = {w4.x, w4.y, w4.z, w4.w};
        float nn[4] = {n4.x, n4.y, n4.z, n4.w};
        float pp[4] = {p4.x, p4.y, p4.z, p4.w};
#pragma unroll
        for (int i = 0; i < 4; ++i)
#pragma unroll
            for (int j = 0; j < 4; ++j) {
                an[i][j] += w[i] * nn[j];
                ap[i][j] += w[i] * pp[j];
            }
    }
    int sec = (r0 % 192) / 64;          // 0=q 1=k 2=v
    int h = r0 / 192, bh = b * 8 + h;
    float sc = (sec == 0) ? 0.18033688f : 1.0f;   // 0.125 * log2(e) for Q
#pragma unroll
    for (int i = 0; i < 4; ++i) {
        float4 x4 = xq[i];
        an[i][0] = (an[i][0] + x4.x) * sc; an[i][1] = (an[i][1] + x4.y) * sc;
        an[i][2] = (an[i][2] + x4.z) * sc; an[i][3] = (an[i][3] + x4.w) * sc;
        ap[i][0] = (ap[i][0] + x4.x) * sc; ap[i][1] = (ap[i][1] + x4.y) * sc;
        ap[i][2] = (ap[i][2] + x4.z) * sc; ap[i][3] = (ap[i][3] + x4.w) * sc;
    }
    if (sec == 2) {
        short* Vn = wsS + VNCS_OFF + bh * NT;
#pragma unroll
        for (int i = 0; i < 4; ++i) {
            int c = tr * 4 + i;
            uint2 pk; pk.x = p2(an[i][0], an[i][1]); pk.y = p2(an[i][2], an[i][3]);
            *(uint2*)&Vn[c * TT + t0 + tc * 4] = pk;
        }
        short* dst = wsS + VFT_OFF + bh * NT + t0 * 64;
        __syncthreads();
#pragma unroll
        for (int i = 0; i < 4; ++i)
#pragma unroll
            for (int j = 0; j < 4; ++j)
                sbufB[(tc * 4 + j) * 72 + tr * 4 + i] = f2bf(ap[i][j]);
        __syncthreads();
#pragma unroll
        for (int rep = 0; rep < 2; ++rep) {
            int idx = rep * 256 + tid; int tl = idx >> 3, c8 = idx & 7;
            *(short8*)&dst[tl * 64 + c8 * 8] = *(const short8*)&sbufB[tl * 72 + c8 * 8];
        }
    } else {
        short* dn = wsS + (sec == 0 ? QNT_OFF : KNT_OFF) + bh * NT + t0 * 64;
        short* df = wsS + (sec == 0 ? QFT_OFF : KFT_OFF) + bh * NT + t0 * 64;
        __syncthreads();
#pragma unroll
        for (int i = 0; i < 4; ++i)
#pragma unroll
            for (int j = 0; j < 4; ++j) {
                sbufA[(tc * 4 + j) * 72 + tr * 4 + i] = f2bf(an[i][j]);
                sbufB[(tc * 4 + j) * 72 + tr * 4 + i] = f2bf(ap[i][j]);
            }
        __syncthreads();
#pragma unroll
        for (int rep = 0; rep < 2; ++rep) {
            int idx = rep * 256 + tid; int tl = idx >> 3, c8 = idx & 7;
            *(short8*)&dn[tl * 64 + c8 * 8] = *(const short8*)&sbufA[tl * 72 + c8 * 8];
            *(short8*)&df[tl * 64 + c8 * 8] = *(const short8*)&sbufB[tl * 72 + c8 * 8];
        }
    }
}

// ---------------------------------------------------------------------------
// Kernel 2: null attention for UNCOVERED rows only. grid (32 bh, 64 rowblocks
// of 16), 256 threads. All MFMA operands loaded DIRECTLY from global (L2,
// XCD-pinned): zero barriers in K-loop. Wave w handles col-tiles 4w..4w+3;
// partials (m=0 softmax => plain sums) reduced across waves via LDS.
// ---------------------------------------------------------------------------
__global__ __launch_bounds__(256)
void attn_null_u(const short* __restrict__ wsS,
                 const unsigned short* __restrict__ ulist,
                 const int* __restrict__ ucnt, float* __restrict__ out) {
    __shared__ __align__(16) short Ps[4 * 1152];    // per-wave [16][72]
    __shared__ float Rbuf[3][64][20];               // waves 1..3 partials
    int bh = blockIdx.x, rt = blockIdx.y;
    int b = bh >> 3, h = bh & 7;
    int U = ucnt[b];
    int n0 = rt * 16;
    if (n0 >= U) return;
    int tid = threadIdx.x;
    int w = tid >> 6, lane = tid & 63, ln = lane & 15, qd = lane >> 4;
    const short* QnT = wsS + QNT_OFF + bh * NT;
    const short* KnT = wsS + KNT_OFF + bh * NT;
    const short* Vn  = wsS + VNCS_OFF + bh * NT;
    const unsigned short* ul = ulist + b * 1024;
    int trow = ul[min(n0 + ln, U - 1)];
    short8 aq0 = *(const short8*)&QnT[trow * 64 + qd * 8];
    short8 aq1 = *(const short8*)&QnT[trow * 64 + 32 + qd * 8];
    v4f O[4]; float l[4];
#pragma unroll
    for (int r = 0; r < 4; ++r) l[r] = 0.f;
#pragma unroll
    for (int cc = 0; cc < 4; ++cc) O[cc] = (v4f){0.f, 0.f, 0.f, 0.f};
    short* Pw = Ps + w * 1152;
#pragma unroll
    for (int i = 0; i < 4; ++i) {
        int s0 = (w * 4 + i) * 64;
        short8 kf[4][2], vf[4][2];
#pragma unroll
        for (int nn = 0; nn < 4; ++nn) {
            int base = (s0 + 4 * ln + nn) * 64;      // pi-ordered columns
            kf[nn][0] = *(const short8*)&KnT[base + qd * 8];
            kf[nn][1] = *(const short8*)&KnT[base + 32 + qd * 8];
        }
#pragma unroll
        for (int cc = 0; cc < 4; ++cc) {
            int base = (cc * 16 + ln) * TT + s0;
            vf[cc][0] = *(const short8*)&Vn[base + qd * 8];
            vf[cc][1] = *(const short8*)&Vn[base + 32 + qd * 8];
        }
        v4f S[4];
#pragma unroll
        for (int nn = 0; nn < 4; ++nn) {
            v4f z = (v4f){0.f, 0.f, 0.f, 0.f};
            z = __builtin_amdgcn_mfma_f32_16x16x32_bf16(aq0, kf[nn][0], z, 0, 0, 0);
            z = __builtin_amdgcn_mfma_f32_16x16x32_bf16(aq1, kf[nn][1], z, 0, 0, 0);
            S[nn] = z;
        }
#pragma unroll
        for (int r = 0; r < 4; ++r) {
            float e0 = EXP2(S[0][r]);
            float e1 = EXP2(S[1][r]);
            float e2 = EXP2(S[2][r]);
            float e3 = EXP2(S[3][r]);
            l[r] += e0 + e1 + e2 + e3;
            uint2 pk; pk.x = p2t(e0, e1); pk.y = p2t(e2, e3);
            *(uint2*)&Pw[(qd * 4 + r) * 72 + 4 * ln] = pk;
        }
        short8 ap0 = *(const short8*)&Pw[ln * 72 + qd * 8];
        short8 ap1 = *(const short8*)&Pw[ln * 72 + 32 + qd * 8];
#pragma unroll
        for (int cc = 0; cc < 4; ++cc) {
            O[cc] = __builtin_amdgcn_mfma_f32_16x16x32_bf16(ap0, vf[cc][0], O[cc], 0, 0, 0);
            O[cc] = __builtin_amdgcn_mfma_f32_16x16x32_bf16(ap1, vf[cc][1], O[cc], 0, 0, 0);
        }
    }
#pragma unroll
    for (int r = 0; r < 4; ++r) {
        l[r] += __shfl_xor(l[r], 1, 64);
        l[r] += __shfl_xor(l[r], 2, 64);
        l[r] += __shfl_xor(l[r], 4, 64);
        l[r] += __shfl_xor(l[r], 8, 64);
    }
    if (w > 0) {
#pragma unroll
        for (int cc = 0; cc < 4; ++cc)
#pragma unroll
            for (int r = 0; r < 4; ++r) Rbuf[w - 1][lane][cc * 4 + r] = O[cc][r];
#pragma unroll
        for (int r = 0; r < 4; ++r) Rbuf[w - 1][lane][16 + r] = l[r];
    }
    __syncthreads();
    if (w == 0) {
#pragma unroll
        for (int ww = 0; ww < 3; ++ww) {
#pragma unroll
            for (int cc = 0; cc < 4; ++cc)
#pragma unroll
                for (int r = 0; r < 4; ++r) O[cc][r] += Rbuf[ww][lane][cc * 4 + r];
#pragma unroll
            for (int r = 0; r < 4; ++r) l[r] += Rbuf[ww][lane][16 + r];
        }
        int obase = (b * 512 + h * 64) * TT;
#pragma unroll
        for (int r = 0; r < 4; ++r) {
            int rank = n0 + qd * 4 + r;
            if (rank < U) {
                int t = ul[rank];
                float inv = 1.0f / l[r];
#pragma unroll
                for (int cc = 0; cc < 4; ++cc)
                    out[obase + (cc * 16 + ln) * TT + t] = O[cc][r] * inv;
            }
        }
    }
}

// ---------------------------------------------------------------------------
// Kernel 3: foreground attention (covered rows only). grid (32 bh, 16 strips
// of 64 rows), 256 threads. R7-verified phase-2 structure; epilogue writes
// only covered t's (uncovered written by attn_null_u).
// ---------------------------------------------------------------------------
__global__ __launch_bounds__(256)
void attn_fg(const short* __restrict__ wsS, const float* __restrict__ bboxes,
             float* __restrict__ out) {
    __shared__ __align__(16) short lds[13824];
    __shared__ unsigned short tmap[1024];
    short* Qs = lds;            // [64][72], aliased as Ps (wave-private rows)
    short* Ks = lds + 4608;     // [64][72]  ([s][c], pi-permuted rows)
    short* Vs = lds + 9216;     // [64][72]  ([c][s], natural s)
    int bh = blockIdx.x, rt = blockIdx.y;
    int b = bh >> 3, h = bh & 7;
    int t0 = rt * 64;
    int tid = threadIdx.x;
    int w = tid >> 6, lane = tid & 63, ln = lane & 15, qd = lane >> 4;
    const short* QfT = wsS + QFT_OFF + bh * NT;
    const short* KfT = wsS + KFT_OFF + bh * NT;
    const short* VfT = wsS + VFT_OFF + bh * NT;

    int r0i = 2 * rt, r1i = 2 * rt + 1;
    unsigned inter = 0u, cov0 = 0u, cov1 = 0u;
    for (int o = 0; o < NOBJ; ++o) {
        int i0, j0, hh, ww;
        get_region(&bboxes[(b * NOBJ + o) * 5], i0, j0, hh, ww);
        int i1 = i0 + hh;
        if (i0 <= r1i && i1 > r0i) {
            inter |= (1u << o);
            unsigned wm = (ww >= 32) ? 0xFFFFFFFFu : (((1u << ww) - 1u) << j0);
            if (i0 <= r0i && r0i < i1) cov0 |= wm;
            if (i0 <= r1i && r1i < i1) cov1 |= wm;
        }
    }
    if (inter == 0u) return;

#pragma unroll
    for (int rep = 0; rep < 2; ++rep) {
        int idx = rep * 256 + tid; int cell = idx >> 3, o8 = idx & 7;
        *(short8*)&Qs[cell * 72 + o8 * 8] =
            *(const short8*)&QfT[(t0 + cell) * 64 + o8 * 8];
    }
    __syncthreads();
    short8 aq0 = *(const short8*)&Qs[(16 * w + ln) * 72 + qd * 8];
    short8 aq1 = *(const short8*)&Qs[(16 * w + ln) * 72 + 32 + qd * 8];
    v4f Oacc[4]; float cnt[4];
#pragma unroll
    for (int r = 0; r < 4; ++r) cnt[r] = 0.f;
#pragma unroll
    for (int cc = 0; cc < 4; ++cc) Oacc[cc] = (v4f){0.f, 0.f, 0.f, 0.f};

    for (int o = 0; o < NOBJ; ++o) {
        if (!((inter >> o) & 1u)) continue;
        int i0, j0, hh, ww;
        get_region(&bboxes[(b * NOBJ + o) * 5], i0, j0, hh, ww);
        int i1 = i0 + hh;
        int R = hh * ww;
        for (int idx = tid; idx < R; idx += 256) {
            int ri = idx / ww; int rj = idx - ri * ww;
            tmap[idx] = (unsigned short)((i0 + ri) * 32 + j0 + rj);
        }
        __syncthreads();
        v4f O[4]; float l[4];
#pragma unroll
        for (int r = 0; r < 4; ++r) l[r] = 0.f;
#pragma unroll
        for (int cc = 0; cc < 4; ++cc) O[cc] = (v4f){0.f, 0.f, 0.f, 0.f};
        int nct = (R + 63) >> 6;
        short8 kreg[2], vreg[2];
#pragma unroll
        for (int rep = 0; rep < 2; ++rep) {
            int idx = rep * 256 + tid; int cell = idx >> 3, o8 = idx & 7;
            int pc = 4 * (cell & 15) + (cell >> 4);
            int tk = tmap[min(pc, R - 1)];
            int tv = tmap[min(cell, R - 1)];
            kreg[rep] = *(const short8*)&KfT[tk * 64 + o8 * 8];
            vreg[rep] = *(const short8*)&VfT[tv * 64 + o8 * 8];
        }
        for (int ct = 0; ct < nct; ++ct) {
            int sb = ct * 64;
            __syncthreads();
#pragma unroll
            for (int rep = 0; rep < 2; ++rep) {
                int idx = rep * 256 + tid; int cell = idx >> 3, o8 = idx & 7;
                *(short8*)&Ks[cell * 72 + o8 * 8] = kreg[rep];
#pragma unroll
                for (int jj = 0; jj < 8; ++jj) {   // rotated transpose scatter
                    int j = (jj + o8) & 7;
                    Vs[(o8 * 8 + j) * 72 + cell] = vreg[rep][j];
                }
            }
            __syncthreads();
            if (ct + 1 < nct) {
                int s0 = sb + 64;
#pragma unroll
                for (int rep = 0; rep < 2; ++rep) {
                    int idx = rep * 256 + tid; int cell = idx >> 3, o8 = idx & 7;
                    int pc = 4 * (cell & 15) + (cell >> 4);
                    int tk = tmap[min(s0 + pc, R - 1)];
                    int tv = tmap[min(s0 + cell, R - 1)];
                    kreg[rep] = *(const short8*)&KfT[tk * 64 + o8 * 8];
                    vreg[rep] = *(const short8*)&VfT[tv * 64 + o8 * 8];
                }
            }
            v4f S[4];
#pragma unroll
            for (int nn = 0; nn < 4; ++nn) {
                short8 b0 = *(const short8*)&Ks[(nn * 16 + ln) * 72 + qd * 8];
                short8 b1 = *(const short8*)&Ks[(nn * 16 + ln) * 72 + 32 + qd * 8];
                v4f z = (v4f){0.f, 0.f, 0.f, 0.f};
                z = __builtin_amdgcn_mfma_f32_16x16x32_bf16(aq0, b0, z, 0, 0, 0);
                z = __builtin_amdgcn_mfma_f32_16x16x32_bf16(aq1, b1, z, 0, 0, 0);
                S[nn] = z;
            }
            float v0 = (sb + 4 * ln + 0) < R ? 1.f : 0.f;
            float v1 = (sb + 4 * ln + 1) < R ? 1.f : 0.f;
            float v2 = (sb + 4 * ln + 2) < R ? 1.f : 0.f;
            float v3 = (sb + 4 * ln + 3) < R ? 1.f : 0.f;
#pragma unroll
            for (int r = 0; r < 4; ++r) {
                float e0 = EXP2(S[0][r]) * v0;
                float e1 = EXP2(S[1][r]) * v1;
                float e2 = EXP2(S[2][r]) * v2;
                float e3 = EXP2(S[3][r]) * v3;
                l[r] += e0 + e1 + e2 + e3;
                uint2 pk; pk.x = p2t(e0, e1); pk.y = p2t(e2, e3);
                *(uint2*)&Qs[(w * 16 + 4 * qd + r) * 72 + 4 * ln] = pk;
            }
            short8 ap0 = *(const short8*)&Qs[(w * 16 + ln) * 72 + qd * 8];
            short8 ap1 = *(const short8*)&Qs[(w * 16 + ln) * 72 + 32 + qd * 8];
#pragma unroll
            for (int cc = 0; cc < 4; ++cc) {
                short8 bv0 = *(const short8*)&Vs[(cc * 16 + ln) * 72 + qd * 8];
                short8 bv1 = *(const short8*)&Vs[(cc * 16 + ln) * 72 + 32 + qd * 8];
                O[cc] = __builtin_amdgcn_mfma_f32_16x16x32_bf16(ap0, bv0, O[cc], 0, 0, 0);
                O[cc] = __builtin_amdgcn_mfma_f32_16x16x32_bf16(ap1, bv1, O[cc], 0, 0, 0);
            }
        }
#pragma unroll
        for (int r = 0; r < 4; ++r) {
            float rs = l[r];
            rs += __shfl_xor(rs, 1, 64);
            rs += __shfl_xor(rs, 2, 64);
            rs += __shfl_xor(rs, 4, 64);
            rs += __shfl_xor(rs, 8, 64);
            float inv = 1.0f / rs;
            int t = t0 + 16 * w + 4 * qd + r;
            int ti = t >> 5, tj = t & 31;
            bool in = (ti >= i0) && (ti < i1) && (tj >= j0) && (tj < j0 + ww);
            if (in) {
                cnt[r] += 1.f;
#pragma unroll
                for (int cc = 0; cc < 4; ++cc) Oacc[cc][r] += O[cc][r] * inv;
            }
        }
    }

    // Epilogue: write covered t's only (uncovered owned by attn_null_u)
    __syncthreads();
    float* Ot = (float*)lds;   // [64][68] floats = 17408 B
#pragma unroll
    for (int r = 0; r < 4; ++r) {
        int tl = 16 * w + 4 * qd + r;
        float icnt = cnt[r] > 0.f ? 1.0f / cnt[r] : 0.f;
#pragma unroll
        for (int cc = 0; cc < 4; ++cc)
            Ot[(cc * 16 + ln) * 68 + tl] = Oacc[cc][r] * icnt;
    }
    __syncthreads();
    int obase = (b * 512 + h * 64) * TT + t0;
#pragma unroll
    for (int rep = 0; rep < 4; ++rep) {
        int idx = rep * 256 + tid; int c = idx >> 4, t4 = (idx & 15) * 4;
#pragma unroll
        for (int j = 0; j < 4; ++j) {
            int tl = t4 + j;
            unsigned cv = (tl < 32) ? cov0 : cov1;
            if ((cv >> (tl & 31)) & 1u)
                out[obase + c * TT + tl] = Ot[c * 68 + tl];
        }
    }
}

extern "C" void kernel_launch(void* const* d_in, const int* in_sizes, int n_in,
                              void* d_out, int out_size, void* d_ws, size_t ws_size,
                              hipStream_t stream) {
    const float* qkv    = (const float*)d_in[0];
    const float* bboxes = (const float*)d_in[1];
    const float* nEmb   = (const float*)d_in[2];
    const float* pEmb   = (const float*)d_in[3];
    const float* W      = (const float*)d_in[4];
    short* wsS = (short*)d_ws;
    unsigned short* ulist = (unsigned short*)(wsS + ULIST_OFF);
    int* ucntp = (int*)((char*)d_ws + UCNT_BYTE_OFF);
    float* out = (float*)d_out;

    list_kernel<<<4, 256, 0, stream>>>(bboxes, ulist, ucntp);
    fuse_kernel<<<dim3(16, 24, 4), 256, 0, stream>>>(qkv, nEmb, pEmb, W, wsS);
    attn_null_u<<<dim3(32, 64), 256, 0, stream>>>(wsS, ulist, ucntp, out);
    attn_fg<<<dim3(32, 16), 256, 0, stream>>>(wsS, bboxes, out);
}

// Round 9
// 161.225 us; speedup vs baseline: 1.1663x; 1.1663x over previous
//
#include <hip/hip_runtime.h>
#include <math.h>

// Problem constants (fixed by setup_inputs)
#define BS 4
#define NH 8
#define TT 1024         // T = 32*32
#define WROWS 1536      // 3*NH*CH
#define NOBJ 8
#define NT 65536        // per-bh tensor elems (64*1024)

// Workspace layout (short element offsets)
#define QNT_OFF  0
#define KNT_OFF  2097152
#define VNCS_OFF 4194304
#define QFT_OFF  6291456
#define KFT_OFF  8388608
#define VFT_OFF  10485760

typedef __attribute__((ext_vector_type(8))) short short8;
typedef __attribute__((ext_vector_type(4))) float v4f;

#if __has_builtin(__builtin_amdgcn_exp2f)
#define EXP2(x) __builtin_amdgcn_exp2f(x)
#else
#define EXP2(x) exp2f(x)
#endif

__device__ __forceinline__ short f2bf(float f) {
    unsigned u = __float_as_uint(f);
    u = (u + 0x7FFF + ((u >> 16) & 1)) >> 16;   // RNE
    return (short)u;
}
__device__ __forceinline__ unsigned p2(float a, float b) {
    return (unsigned)(unsigned short)f2bf(a) | ((unsigned)(unsigned short)f2bf(b) << 16);
}
// truncating bf16 pack (P matrix only; l summed in fp32)
__device__ __forceinline__ unsigned p2t(float a, float b) {
    return (__float_as_uint(a) >> 16) | (__float_as_uint(b) & 0xFFFF0000u);
}

__device__ __forceinline__ void get_region(const float* __restrict__ bb,
                                           int& i0, int& j0, int& hh, int& ww) {
    float x = bb[0], y = bb[1], bw = bb[2], bh = bb[3];
    float i0f = fminf(31.0f, floorf(y * 32.0f));
    float j0f = fminf(31.0f, floorf(x * 32.0f));
    float i1f = i0f + fmaxf(1.0f, ceilf(bh * 32.0f));
    float j1f = j0f + fmaxf(1.0f, ceilf(bw * 32.0f));
    i0 = (int)i0f; j0 = (int)j0f;
    int i1 = min(32, (int)i1f);
    int j1 = min(32, (int)j1f);
    hh = i1 - i0; ww = j1 - j0;
}

// ---------------------------------------------------------------------------
// Kernel 1: fused projection + layout conversion to bf16 (verified R7).
// Q sections carry 0.125*log2(e) so attention uses exp2 directly.
// ---------------------------------------------------------------------------
__global__ __launch_bounds__(256)
void fuse_kernel(const float* __restrict__ qkv, const float* __restrict__ nEmb,
                 const float* __restrict__ pEmb, const float* __restrict__ W,
                 short* __restrict__ wsS) {
    __shared__ float WtT[64][68];
    __shared__ float En[64][64];
    __shared__ float Ep[64][64];
    short* sbufA = (short*)&WtT[0][0];
    short* sbufB = (short*)&En[0][0];
    int t0 = blockIdx.x * 64;
    int r0 = blockIdx.y * 64;
    int b  = blockIdx.z;
    int tid = threadIdx.x;
    int half = tid >> 4;
    int q4 = (tid & 15) * 4;
    int tr = tid >> 4, tc = tid & 15;
    float4 xq[4];
#pragma unroll
    for (int i = 0; i < 4; ++i)
        xq[i] = *(const float4*)&qkv[(b * WROWS + r0 + tr * 4 + i) * TT + t0 + tc * 4];
#pragma unroll
    for (int p = 0; p < 4; ++p) {
        int rr = p * 16 + half;
        float4 w4 = *(const float4*)&W[(r0 + rr) * 64 + q4];
        WtT[q4 + 0][rr] = w4.x; WtT[q4 + 1][rr] = w4.y;
        WtT[q4 + 2][rr] = w4.z; WtT[q4 + 3][rr] = w4.w;
        int e = p * 16 + half;
        *(float4*)&En[e][q4] = *(const float4*)&nEmb[(b * 64 + e) * TT + t0 + q4];
        *(float4*)&Ep[e][q4] = *(const float4*)&pEmb[(b * 64 + e) * TT + t0 + q4];
    }
    __syncthreads();
    float an[4][4] = {{0.f}}, ap[4][4] = {{0.f}};
#pragma unroll 8
    for (int e = 0; e < 64; ++e) {
        float4 w4 = *(const float4*)&WtT[e][tr * 4];
        float4 n4 = *(const float4*)&En[e][tc * 4];
        float4 p4 = *(const float4*)&Ep[e][tc * 4];
        float w[4]  = {w4.x, w4.y, w4.z, w4.w};
        float nn[4] = {n4.x, n4.y, n4.z, n4.w};
        float pp[4] = {p4.x, p4.y, p4.z, p4.w};
#pragma unroll
        for (int i = 0; i < 4; ++i)
#pragma unroll
            for (int j = 0; j < 4; ++j) {
                an[i][j] += w[i] * nn[j];
                ap[i][j] += w[i] * pp[j];
            }
    }
    int sec = (r0 % 192) / 64;          // 0=q 1=k 2=v
    int h = r0 / 192, bh = b * 8 + h;
    float sc = (sec == 0) ? 0.18033688f : 1.0f;   // 0.125 * log2(e) for Q
#pragma unroll
    for (int i = 0; i < 4; ++i) {
        float4 x4 = xq[i];
        an[i][0] = (an[i][0] + x4.x) * sc; an[i][1] = (an[i][1] + x4.y) * sc;
        an[i][2] = (an[i][2] + x4.z) * sc; an[i][3] = (an[i][3] + x4.w) * sc;
        ap[i][0] = (ap[i][0] + x4.x) * sc; ap[i][1] = (ap[i][1] + x4.y) * sc;
        ap[i][2] = (ap[i][2] + x4.z) * sc; ap[i][3] = (ap[i][3] + x4.w) * sc;
    }
    if (sec == 2) {
        short* Vn = wsS + VNCS_OFF + bh * NT;
#pragma unroll
        for (int i = 0; i < 4; ++i) {
            int c = tr * 4 + i;
            uint2 pk; pk.x = p2(an[i][0], an[i][1]); pk.y = p2(an[i][2], an[i][3]);
            *(uint2*)&Vn[c * TT + t0 + tc * 4] = pk;
        }
        short* dst = wsS + VFT_OFF + bh * NT + t0 * 64;
        __syncthreads();
#pragma unroll
        for (int i = 0; i < 4; ++i)
#pragma unroll
            for (int j = 0; j < 4; ++j)
                sbufB[(tc * 4 + j) * 72 + tr * 4 + i] = f2bf(ap[i][j]);
        __syncthreads();
#pragma unroll
        for (int rep = 0; rep < 2; ++rep) {
            int idx = rep * 256 + tid; int tl = idx >> 3, c8 = idx & 7;
            *(short8*)&dst[tl * 64 + c8 * 8] = *(const short8*)&sbufB[tl * 72 + c8 * 8];
        }
    } else {
        short* dn = wsS + (sec == 0 ? QNT_OFF : KNT_OFF) + bh * NT + t0 * 64;
        short* df = wsS + (sec == 0 ? QFT_OFF : KFT_OFF) + bh * NT + t0 * 64;
        __syncthreads();
#pragma unroll
        for (int i = 0; i < 4; ++i)
#pragma unroll
            for (int j = 0; j < 4; ++j) {
                sbufA[(tc * 4 + j) * 72 + tr * 4 + i] = f2bf(an[i][j]);
                sbufB[(tc * 4 + j) * 72 + tr * 4 + i] = f2bf(ap[i][j]);
            }
        __syncthreads();
#pragma unroll
        for (int rep = 0; rep < 2; ++rep) {
            int idx = rep * 256 + tid; int tl = idx >> 3, c8 = idx & 7;
            *(short8*)&dn[tl * 64 + c8 * 8] = *(const short8*)&sbufA[tl * 72 + c8 * 8];
            *(short8*)&df[tl * 64 + c8 * 8] = *(const short8*)&sbufB[tl * 72 + c8 * 8];
        }
    }
}

// ---------------------------------------------------------------------------
// Kernel 2: split-phase attention in ONE dispatch. grid (32 bh, 16 strips,
// 2 phases), 256 threads. z==0: fg path (covered cells; dispatched first —
// it owns the tail). z==1: null path (uncovered cells). Writes are disjoint
// (covered vs uncovered), so no combine and no atomics. Both phases use the
// verified LDS-staged pipeline; same-bh blocks pinned to one XCD (id%8=bh%8).
// ---------------------------------------------------------------------------
__global__ __launch_bounds__(256)
void attn_split(const short* __restrict__ wsS, const float* __restrict__ bboxes,
                float* __restrict__ out) {
    __shared__ __align__(16) short lds[13824];
    __shared__ unsigned short tmap[1024];
    short* Qs = lds;            // [64][72], aliased as Ps (wave-private rows)
    short* Ks = lds + 4608;     // [64][72]  ([s][c], pi-permuted rows)
    short* Vs = lds + 9216;     // [64][72]  ([c][s], natural s)
    int bh = blockIdx.x, rt = blockIdx.y, phase = blockIdx.z;
    int b = bh >> 3, h = bh & 7;
    int t0 = rt * 64;
    int tid = threadIdx.x;
    int w = tid >> 6, lane = tid & 63, ln = lane & 15, qd = lane >> 4;

    // ---- object analysis for this strip (image rows 2rt, 2rt+1) ----
    int r0i = 2 * rt, r1i = 2 * rt + 1;
    unsigned inter = 0u, cov0 = 0u, cov1 = 0u;
    for (int o = 0; o < NOBJ; ++o) {
        int i0, j0, hh, ww;
        get_region(&bboxes[(b * NOBJ + o) * 5], i0, j0, hh, ww);
        int i1 = i0 + hh;
        if (i0 <= r1i && i1 > r0i) {
            inter |= (1u << o);
            unsigned wm = (ww >= 32) ? 0xFFFFFFFFu : (((1u << ww) - 1u) << j0);
            if (i0 <= r0i && r0i < i1) cov0 |= wm;
            if (i0 <= r1i && r1i < i1) cov1 |= wm;
        }
    }
    int obase = (b * 512 + h * 64) * TT + t0;

    if (phase == 0) {
        // ================= FG path: covered cells =================
        if (inter == 0u) return;
        const short* QfT = wsS + QFT_OFF + bh * NT;
        const short* KfT = wsS + KFT_OFF + bh * NT;
        const short* VfT = wsS + VFT_OFF + bh * NT;
#pragma unroll
        for (int rep = 0; rep < 2; ++rep) {
            int idx = rep * 256 + tid; int cell = idx >> 3, o8 = idx & 7;
            *(short8*)&Qs[cell * 72 + o8 * 8] =
                *(const short8*)&QfT[(t0 + cell) * 64 + o8 * 8];
        }
        __syncthreads();
        short8 aq0 = *(const short8*)&Qs[(16 * w + ln) * 72 + qd * 8];
        short8 aq1 = *(const short8*)&Qs[(16 * w + ln) * 72 + 32 + qd * 8];
        v4f Oacc[4]; float cnt[4];
#pragma unroll
        for (int r = 0; r < 4; ++r) cnt[r] = 0.f;
#pragma unroll
        for (int cc = 0; cc < 4; ++cc) Oacc[cc] = (v4f){0.f, 0.f, 0.f, 0.f};

        for (int o = 0; o < NOBJ; ++o) {
            if (!((inter >> o) & 1u)) continue;
            int i0, j0, hh, ww;
            get_region(&bboxes[(b * NOBJ + o) * 5], i0, j0, hh, ww);
            int i1 = i0 + hh;
            int R = hh * ww;
            for (int idx = tid; idx < R; idx += 256) {
                int ri = idx / ww; int rj = idx - ri * ww;
                tmap[idx] = (unsigned short)((i0 + ri) * 32 + j0 + rj);
            }
            __syncthreads();
            v4f O[4]; float l[4];
#pragma unroll
            for (int r = 0; r < 4; ++r) l[r] = 0.f;
#pragma unroll
            for (int cc = 0; cc < 4; ++cc) O[cc] = (v4f){0.f, 0.f, 0.f, 0.f};
            int nct = (R + 63) >> 6;
            short8 kreg[2], vreg[2];
#pragma unroll
            for (int rep = 0; rep < 2; ++rep) {
                int idx = rep * 256 + tid; int cell = idx >> 3, o8 = idx & 7;
                int pc = 4 * (cell & 15) + (cell >> 4);
                int tk = tmap[min(pc, R - 1)];
                int tv = tmap[min(cell, R - 1)];
                kreg[rep] = *(const short8*)&KfT[tk * 64 + o8 * 8];
                vreg[rep] = *(const short8*)&VfT[tv * 64 + o8 * 8];
            }
            for (int ct = 0; ct < nct; ++ct) {
                int sb = ct * 64;
                __syncthreads();
#pragma unroll
                for (int rep = 0; rep < 2; ++rep) {
                    int idx = rep * 256 + tid; int cell = idx >> 3, o8 = idx & 7;
                    *(short8*)&Ks[cell * 72 + o8 * 8] = kreg[rep];
#pragma unroll
                    for (int jj = 0; jj < 8; ++jj) {   // rotated transpose scatter
                        int j = (jj + o8) & 7;
                        Vs[(o8 * 8 + j) * 72 + cell] = vreg[rep][j];
                    }
                }
                __syncthreads();
                if (ct + 1 < nct) {
                    int s0 = sb + 64;
#pragma unroll
                    for (int rep = 0; rep < 2; ++rep) {
                        int idx = rep * 256 + tid; int cell = idx >> 3, o8 = idx & 7;
                        int pc = 4 * (cell & 15) + (cell >> 4);
                        int tk = tmap[min(s0 + pc, R - 1)];
                        int tv = tmap[min(s0 + cell, R - 1)];
                        kreg[rep] = *(const short8*)&KfT[tk * 64 + o8 * 8];
                        vreg[rep] = *(const short8*)&VfT[tv * 64 + o8 * 8];
                    }
                }
                v4f S[4];
#pragma unroll
                for (int nn = 0; nn < 4; ++nn) {
                    short8 b0 = *(const short8*)&Ks[(nn * 16 + ln) * 72 + qd * 8];
                    short8 b1 = *(const short8*)&Ks[(nn * 16 + ln) * 72 + 32 + qd * 8];
                    v4f z = (v4f){0.f, 0.f, 0.f, 0.f};
                    z = __builtin_amdgcn_mfma_f32_16x16x32_bf16(aq0, b0, z, 0, 0, 0);
                    z = __builtin_amdgcn_mfma_f32_16x16x32_bf16(aq1, b1, z, 0, 0, 0);
                    S[nn] = z;
                }
                float v0 = (sb + 4 * ln + 0) < R ? 1.f : 0.f;
                float v1 = (sb + 4 * ln + 1) < R ? 1.f : 0.f;
                float v2 = (sb + 4 * ln + 2) < R ? 1.f : 0.f;
                float v3 = (sb + 4 * ln + 3) < R ? 1.f : 0.f;
#pragma unroll
                for (int r = 0; r < 4; ++r) {
                    float e0 = EXP2(S[0][r]) * v0;
                    float e1 = EXP2(S[1][r]) * v1;
                    float e2 = EXP2(S[2][r]) * v2;
                    float e3 = EXP2(S[3][r]) * v3;
                    l[r] += e0 + e1 + e2 + e3;
                    uint2 pk; pk.x = p2t(e0, e1); pk.y = p2t(e2, e3);
                    *(uint2*)&Qs[(w * 16 + 4 * qd + r) * 72 + 4 * ln] = pk;
                }
                short8 ap0 = *(const short8*)&Qs[(w * 16 + ln) * 72 + qd * 8];
                short8 ap1 = *(const short8*)&Qs[(w * 16 + ln) * 72 + 32 + qd * 8];
#pragma unroll
                for (int cc = 0; cc < 4; ++cc) {
                    short8 bv0 = *(const short8*)&Vs[(cc * 16 + ln) * 72 + qd * 8];
                    short8 bv1 = *(const short8*)&Vs[(cc * 16 + ln) * 72 + 32 + qd * 8];
                    O[cc] = __builtin_amdgcn_mfma_f32_16x16x32_bf16(ap0, bv0, O[cc], 0, 0, 0);
                    O[cc] = __builtin_amdgcn_mfma_f32_16x16x32_bf16(ap1, bv1, O[cc], 0, 0, 0);
                }
            }
#pragma unroll
            for (int r = 0; r < 4; ++r) {
                float rs = l[r];
                rs += __shfl_xor(rs, 1, 64);
                rs += __shfl_xor(rs, 2, 64);
                rs += __shfl_xor(rs, 4, 64);
                rs += __shfl_xor(rs, 8, 64);
                float inv = 1.0f / rs;
                int t = t0 + 16 * w + 4 * qd + r;
                int ti = t >> 5, tj = t & 31;
                bool in = (ti >= i0) && (ti < i1) && (tj >= j0) && (tj < j0 + ww);
                if (in) {
                    cnt[r] += 1.f;
#pragma unroll
                    for (int cc = 0; cc < 4; ++cc) Oacc[cc][r] += O[cc][r] * inv;
                }
            }
        }
        // Epilogue: write covered t's only
        __syncthreads();
        float* Ot = (float*)lds;   // [64][68] floats
#pragma unroll
        for (int r = 0; r < 4; ++r) {
            int tl = 16 * w + 4 * qd + r;
            float icnt = cnt[r] > 0.f ? 1.0f / cnt[r] : 0.f;
#pragma unroll
            for (int cc = 0; cc < 4; ++cc)
                Ot[(cc * 16 + ln) * 68 + tl] = Oacc[cc][r] * icnt;
        }
        __syncthreads();
#pragma unroll
        for (int rep = 0; rep < 4; ++rep) {
            int idx = rep * 256 + tid; int c = idx >> 4, t4 = (idx & 15) * 4;
#pragma unroll
            for (int j = 0; j < 4; ++j) {
                int tl = t4 + j;
                unsigned cv = (tl < 32) ? cov0 : cov1;
                if ((cv >> (tl & 31)) & 1u)
                    out[obase + c * TT + tl] = Ot[c * 68 + tl];
            }
        }
    } else {
        // ================= NULL path: uncovered cells =================
        if ((cov0 & cov1) == 0xFFFFFFFFu) return;   // strip fully covered
        const short* QnT = wsS + QNT_OFF + bh * NT;
        const short* KnT = wsS + KNT_OFF + bh * NT;
        const short* Vn  = wsS + VNCS_OFF + bh * NT;
#pragma unroll
        for (int rep = 0; rep < 2; ++rep) {
            int idx = rep * 256 + tid; int cell = idx >> 3, o8 = idx & 7;
            *(short8*)&Qs[cell * 72 + o8 * 8] =
                *(const short8*)&QnT[(t0 + cell) * 64 + o8 * 8];
        }
        __syncthreads();
        short8 aq0 = *(const short8*)&Qs[(16 * w + ln) * 72 + qd * 8];
        short8 aq1 = *(const short8*)&Qs[(16 * w + ln) * 72 + 32 + qd * 8];
        v4f O[4]; float l[4];
#pragma unroll
        for (int r = 0; r < 4; ++r) l[r] = 0.f;
#pragma unroll
        for (int cc = 0; cc < 4; ++cc) O[cc] = (v4f){0.f, 0.f, 0.f, 0.f};
        short8 kreg[2], vreg[2];
#pragma unroll
        for (int rep = 0; rep < 2; ++rep) {
            int idx = rep * 256 + tid; int cell = idx >> 3, o8 = idx & 7;
            int pc = 4 * (cell & 15) + (cell >> 4);
            kreg[rep] = *(const short8*)&KnT[pc * 64 + o8 * 8];
            vreg[rep] = *(const short8*)&Vn[cell * TT + o8 * 8];
        }
        for (int ct = 0; ct < 16; ++ct) {
            __syncthreads();
#pragma unroll
            for (int rep = 0; rep < 2; ++rep) {
                int idx = rep * 256 + tid; int cell = idx >> 3, o8 = idx & 7;
                *(short8*)&Ks[cell * 72 + o8 * 8] = kreg[rep];
                *(short8*)&Vs[cell * 72 + o8 * 8] = vreg[rep];
            }
            __syncthreads();
            if (ct < 15) {
                int s0 = (ct + 1) * 64;
#pragma unroll
                for (int rep = 0; rep < 2; ++rep) {
                    int idx = rep * 256 + tid; int cell = idx >> 3, o8 = idx & 7;
                    int pc = 4 * (cell & 15) + (cell >> 4);
                    kreg[rep] = *(const short8*)&KnT[(s0 + pc) * 64 + o8 * 8];
                    vreg[rep] = *(const short8*)&Vn[cell * TT + s0 + o8 * 8];
                }
            }
            v4f S[4];
#pragma unroll
            for (int nn = 0; nn < 4; ++nn) {
                short8 b0 = *(const short8*)&Ks[(nn * 16 + ln) * 72 + qd * 8];
                short8 b1 = *(const short8*)&Ks[(nn * 16 + ln) * 72 + 32 + qd * 8];
                v4f z = (v4f){0.f, 0.f, 0.f, 0.f};
                z = __builtin_amdgcn_mfma_f32_16x16x32_bf16(aq0, b0, z, 0, 0, 0);
                z = __builtin_amdgcn_mfma_f32_16x16x32_bf16(aq1, b1, z, 0, 0, 0);
                S[nn] = z;
            }
#pragma unroll
            for (int r = 0; r < 4; ++r) {
                float e0 = EXP2(S[0][r]);
                float e1 = EXP2(S[1][r]);
                float e2 = EXP2(S[2][r]);
                float e3 = EXP2(S[3][r]);
                l[r] += e0 + e1 + e2 + e3;
                uint2 pk; pk.x = p2t(e0, e1); pk.y = p2t(e2, e3);
                *(uint2*)&Qs[(w * 16 + 4 * qd + r) * 72 + 4 * ln] = pk;
            }
            short8 ap0 = *(const short8*)&Qs[(w * 16 + ln) * 72 + qd * 8];
            short8 ap1 = *(const short8*)&Qs[(w * 16 + ln) * 72 + 32 + qd * 8];
#pragma unroll
            for (int cc = 0; cc < 4; ++cc) {
                short8 bv0 = *(const short8*)&Vs[(cc * 16 + ln) * 72 + qd * 8];
                short8 bv1 = *(const short8*)&Vs[(cc * 16 + ln) * 72 + 32 + qd * 8];
                O[cc] = __builtin_amdgcn_mfma_f32_16x16x32_bf16(ap0, bv0, O[cc], 0, 0, 0);
                O[cc] = __builtin_amdgcn_mfma_f32_16x16x32_bf16(ap1, bv1, O[cc], 0, 0, 0);
            }
        }
#pragma unroll
        for (int r = 0; r < 4; ++r) {
            float rs = l[r];
            rs += __shfl_xor(rs, 1, 64);
            rs += __shfl_xor(rs, 2, 64);
            rs += __shfl_xor(rs, 4, 64);
            rs += __shfl_xor(rs, 8, 64);
            float inv = 1.0f / rs;
#pragma unroll
            for (int cc = 0; cc < 4; ++cc) O[cc][r] *= inv;
        }
        // Epilogue: write UNCOVERED t's only
        __syncthreads();
        float* Ot = (float*)lds;   // [64][68] floats
#pragma unroll
        for (int r = 0; r < 4; ++r) {
            int tl = 16 * w + 4 * qd + r;
#pragma unroll
            for (int cc = 0; cc < 4; ++cc)
                Ot[(cc * 16 + ln) * 68 + tl] = O[cc][r];
        }
        __syncthreads();
#pragma unroll
        for (int rep = 0; rep < 4; ++rep) {
            int idx = rep * 256 + tid; int c = idx >> 4, t4 = (idx & 15) * 4;
#pragma unroll
            for (int j = 0; j < 4; ++j) {
                int tl = t4 + j;
                unsigned cv = (tl < 32) ? cov0 : cov1;
                if (!((cv >> (tl & 31)) & 1u))
                    out[obase + c * TT + tl] = Ot[c * 68 + tl];
            }
        }
    }
}

extern "C" void kernel_launch(void* const* d_in, const int* in_sizes, int n_in,
                              void* d_out, int out_size, void* d_ws, size_t ws_size,
                              hipStream_t stream) {
    const float* qkv    = (const float*)d_in[0];
    const float* bboxes = (const float*)d_in[1];
    const float* nEmb   = (const float*)d_in[2];
    const float* pEmb   = (const float*)d_in[3];
    const float* W      = (const float*)d_in[4];
    short* wsS = (short*)d_ws;
    float* out = (float*)d_out;

    fuse_kernel<<<dim3(16, 24, 4), 256, 0, stream>>>(qkv, nEmb, pEmb, W, wsS);
    attn_split<<<dim3(32, 16, 2), 256, 0, stream>>>(wsS, bboxes, out);
}